// Round 1
// 221.894 us; speedup vs baseline: 1.0024x; 1.0024x over previous
//
#include <hip/hip_runtime.h>

// KAN layer fused as one augmented GEMM:
//   out[n][o] = sum_i silu(x[n][i])*scale_base[o][i]
//            + sum_{i,m} basis_m(x[n][i])*scale_sp[o][i]*coef[o][i][m] + bias[o]
// A_aug (8192 x 5376) f16, W_aug (768 x 5376) f16, k = j*768 + i (j=0: silu, j=1..6: basis)

typedef _Float16 f16;
typedef __attribute__((ext_vector_type(4))) _Float16 f16x4;
typedef __attribute__((ext_vector_type(8))) _Float16 f16x8;
typedef __attribute__((ext_vector_type(4))) float f32x4;

#define NTOK 8192
#define DIN 768
#define DOUT 768
#define KAUG 5376   // 7*768
#define BM 128
#define BN 128
#define BK 32
#define KT (KAUG / BK)  // 168

typedef __attribute__((address_space(1))) void gvoid;
typedef __attribute__((address_space(3))) void lvoid;

// ---------------- silu + 6 basis values for one x ----------------
__device__ __forceinline__ void spline6(float xv, float* __restrict__ B, float& s) {
  s = xv / (1.0f + __expf(-xv));  // silu
  // Cox-de Boor, uniform extended grid t[g] = (g-3)*(2/3) - 1, g=0..9
  const float h = 2.0f / 3.0f;
  float Bb[9];
#pragma unroll
  for (int g = 0; g < 9; ++g) {
    float t0 = (float)(g - 3) * h - 1.0f;
    float t1 = (float)(g - 2) * h - 1.0f;
    Bb[g] = (xv >= t0 && xv < t1) ? 1.0f : 0.0f;
  }
#pragma unroll
  for (int p = 1; p <= 3; ++p) {
    float inv = 1.0f / ((float)p * h);
#pragma unroll
    for (int j = 0; j < 8; ++j) {
      if (j < 9 - p) {  // compile-time fold under unroll
        float tj = (float)(j - 3) * h - 1.0f;
        float tjp1 = (float)(j + p + 1 - 3) * h - 1.0f;
        Bb[j] = (xv - tj) * inv * Bb[j] + (tjp1 - xv) * inv * Bb[j + 1];
      }
    }
  }
#pragma unroll
  for (int m = 0; m < 6; ++m) B[m] = Bb[m];
}

// ---------------- Kernel 1: x -> [silu | 6 basis] f16, x4 vectorized ----------------
__global__ __launch_bounds__(256) void build_A(const float* __restrict__ x,
                                               f16* __restrict__ Aa) {
  int idx = (blockIdx.x * 256 + threadIdx.x) * 4;  // 4 consecutive i, exact grid
  float4 xv = *(const float4*)(x + idx);
  int n = idx / DIN;
  int i = idx - n * DIN;  // multiple of 4; all 4 elems share n (DIN % 4 == 0)

  float B0[6], B1[6], B2[6], B3[6];
  float s0, s1, s2, s3;
  spline6(xv.x, B0, s0);
  spline6(xv.y, B1, s1);
  spline6(xv.z, B2, s2);
  spline6(xv.w, B3, s3);

  size_t base = (size_t)n * KAUG + i;  // 8B-aligned f16 stores
  f16x4 sv = {(f16)s0, (f16)s1, (f16)s2, (f16)s3};
  *(f16x4*)(Aa + base) = sv;
#pragma unroll
  for (int m = 0; m < 6; ++m) {
    f16x4 bv = {(f16)B0[m], (f16)B1[m], (f16)B2[m], (f16)B3[m]};
    *(f16x4*)(Aa + base + (size_t)(m + 1) * DIN) = bv;
  }
}

// ---------------- Kernel 2: pack weights ----------------
__global__ __launch_bounds__(256) void build_W(const float* __restrict__ sb,
                                               const float* __restrict__ ssp,
                                               const float* __restrict__ coef,
                                               f16* __restrict__ Wa) {
  int idx = blockIdx.x * 256 + threadIdx.x;  // o*768 + i, exact grid
  float b = sb[idx];
  float sp = ssp[idx];
  int o = idx / DIN;
  int i = idx - o * DIN;
  size_t base = (size_t)o * KAUG + i;
  Wa[base] = (f16)b;
#pragma unroll
  for (int m = 0; m < 6; ++m)
    Wa[base + (size_t)(m + 1) * DIN] = (f16)(sp * coef[(size_t)idx * 6 + m]);
}

// ---------------- Kernel 3: GEMM C = A_aug * W_aug^T + bias ----------------
// 128x128 tile, 4 waves (2x2 of 64x64), BK=32.
// 2-phase double-buffered pipeline (T3 minimum recipe): stage next tile into the
// OTHER (statically distinct) LDS buffer, compute current, ONE barrier per K-step.
// The barrier's implicit vmcnt(0) drain lands after ds_read+MFMA of the current
// tile -> global load latency hidden instead of serialized.
__global__ __launch_bounds__(256) void kan_gemm(const f16* __restrict__ A,
                                                const f16* __restrict__ W,
                                                const float* __restrict__ bias,
                                                float* __restrict__ out) {
  __shared__ alignas(16) f16 As0[BM * BK];  // 8 KB each, 32 KB total
  __shared__ alignas(16) f16 As1[BM * BK];
  __shared__ alignas(16) f16 Bs0[BN * BK];
  __shared__ alignas(16) f16 Bs1[BN * BK];

  const int tid = threadIdx.x;
  const int wave = tid >> 6;
  const int lane = tid & 63;
  const int m0 = blockIdx.y * BM;
  const int n0 = blockIdx.x * BN;
  const int wm = (wave >> 1) * 64;
  const int wn = (wave & 1) * 64;
  const int r = lane & 15;
  const int q = lane >> 4;

  f32x4 acc[4][4] = {};

  // staging chunk for instr s: c = s*256 + wave*64 + lane; row = c>>2, kblk = c&3
  const int c0 = wave * 64 + lane;
  const int rowA0 = c0 >> 2, kb0 = c0 & 3;
  const int c1 = c0 + 256;
  const int rowA1 = c1 >> 2, kb1 = c1 & 3;

  const f16* gA0 = A + (size_t)(m0 + rowA0) * KAUG + kb0 * 8;
  const f16* gA1 = A + (size_t)(m0 + rowA1) * KAUG + kb1 * 8;
  const f16* gB0 = W + (size_t)(n0 + rowA0) * KAUG + kb0 * 8;
  const f16* gB1 = W + (size_t)(n0 + rowA1) * KAUG + kb1 * 8;

  const int wo = wave * 512;  // wave-uniform LDS base (f16 units; 1024 B)

#define STAGE(AS, BS, ktile)                                                             \
  do {                                                                                   \
    const int koff = (ktile)*BK;                                                         \
    __builtin_amdgcn_global_load_lds((gvoid*)(gA0 + koff), (lvoid*)(AS + wo), 16, 0, 0); \
    __builtin_amdgcn_global_load_lds((gvoid*)(gA1 + koff), (lvoid*)(AS + wo + 2048), 16, \
                                     0, 0);                                              \
    __builtin_amdgcn_global_load_lds((gvoid*)(gB0 + koff), (lvoid*)(BS + wo), 16, 0, 0); \
    __builtin_amdgcn_global_load_lds((gvoid*)(gB1 + koff), (lvoid*)(BS + wo + 2048), 16, \
                                     0, 0);                                              \
  } while (0)

#define COMPUTE(AS, BS)                                                                  \
  do {                                                                                   \
    f16x8 af[4], bf[4];                                                                  \
    _Pragma("unroll") for (int mi = 0; mi < 4; ++mi) af[mi] =                            \
        *(const f16x8*)&AS[(wm + mi * 16 + r) * BK + q * 8];                             \
    _Pragma("unroll") for (int ni = 0; ni < 4; ++ni) bf[ni] =                            \
        *(const f16x8*)&BS[(wn + ni * 16 + r) * BK + q * 8];                             \
    _Pragma("unroll") for (int mi = 0; mi < 4; ++mi) _Pragma("unroll") for (int ni = 0;  \
                                                                            ni < 4;     \
                                                                            ++ni)       \
        acc[mi][ni] =                                                                    \
        __builtin_amdgcn_mfma_f32_16x16x32_f16(af[mi], bf[ni], acc[mi][ni], 0, 0, 0);    \
  } while (0)

  STAGE(As0, Bs0, 0);
  __syncthreads();  // drain prologue staging

  for (int kt = 0; kt < KT; kt += 2) {  // KT even; kt+1 always valid
    STAGE(As1, Bs1, kt + 1);            // prefetch next tile (async, in flight)
    COMPUTE(As0, Bs0);                  // reads distinct buffer -> no wait needed
    __syncthreads();                    // drains As1/Bs1 staging + read-fence As0/Bs0
    if (kt + 2 < KT) STAGE(As0, Bs0, kt + 2);
    COMPUTE(As1, Bs1);
    __syncthreads();
  }

#undef STAGE
#undef COMPUTE

  // epilogue: D mapping col = lane&15, row = q*4 + reg
#pragma unroll
  for (int mi = 0; mi < 4; ++mi) {
#pragma unroll
    for (int ni = 0; ni < 4; ++ni) {
      const int gcol = n0 + wn + ni * 16 + r;
      const float bv = bias[gcol];
#pragma unroll
      for (int rg = 0; rg < 4; ++rg) {
        const int grow = m0 + wm + mi * 16 + q * 4 + rg;
        out[(size_t)grow * DOUT + gcol] = acc[mi][ni][rg] + bv;
      }
    }
  }
}

extern "C" void kernel_launch(void* const* d_in, const int* in_sizes, int n_in,
                              void* d_out, int out_size, void* d_ws, size_t ws_size,
                              hipStream_t stream) {
  const float* x = (const float*)d_in[0];           // (4,2048,768)
  const float* coef = (const float*)d_in[1];        // (768,768,6)
  const float* scale_base = (const float*)d_in[2];  // (768,768)
  const float* scale_sp = (const float*)d_in[3];    // (768,768)
  const float* bias = (const float*)d_in[4];        // (768,)
  float* out = (float*)d_out;                       // (8192,768)

  f16* Aa = (f16*)d_ws;                                     // 8192*5376*2 = 88.1 MB
  f16* Wa = (f16*)((char*)d_ws + (size_t)NTOK * KAUG * 2);  // 768*5376*2  = 8.3 MB

  build_A<<<(NTOK * DIN) / (256 * 4), 256, 0, stream>>>(x, Aa);
  build_W<<<(DOUT * DIN) / 256, 256, 0, stream>>>(scale_base, scale_sp, coef, Wa);
  kan_gemm<<<dim3(DOUT / BN, NTOK / BM), 256, 0, stream>>>(Aa, Wa, bias, out);
}

// Round 2
// 212.070 us; speedup vs baseline: 1.0488x; 1.0463x over previous
//
#include <hip/hip_runtime.h>

// KAN layer fused as one augmented GEMM:
//   out[n][o] = sum_i silu(x[n][i])*scale_base[o][i]
//            + sum_{i,m} basis_m(x[n][i])*scale_sp[o][i]*coef[o][i][m] + bias[o]
// A_aug (8192 x 5376) f16, W_aug (768 x 5376) f16, k = j*768 + i (j=0: silu, j=1..6: basis)

typedef _Float16 f16;
typedef __attribute__((ext_vector_type(4))) _Float16 f16x4;
typedef __attribute__((ext_vector_type(8))) _Float16 f16x8;
typedef __attribute__((ext_vector_type(4))) float f32x4;

#define NTOK 8192
#define DIN 768
#define DOUT 768
#define KAUG 5376   // 7*768
#define BM 64
#define BN 128
#define BK 32
#define KT (KAUG / BK)  // 168
#define NBLK ((NTOK / BM) * (DOUT / BN))  // 128*6 = 768 = exactly 3 blocks/CU

typedef __attribute__((address_space(1))) void gvoid;
typedef __attribute__((address_space(3))) void lvoid;

// ---------------- silu + 6 basis values for one x ----------------
__device__ __forceinline__ void spline6(float xv, float* __restrict__ B, float& s) {
  s = xv / (1.0f + __expf(-xv));  // silu
  // Cox-de Boor, uniform extended grid t[g] = (g-3)*(2/3) - 1, g=0..9
  const float h = 2.0f / 3.0f;
  float Bb[9];
#pragma unroll
  for (int g = 0; g < 9; ++g) {
    float t0 = (float)(g - 3) * h - 1.0f;
    float t1 = (float)(g - 2) * h - 1.0f;
    Bb[g] = (xv >= t0 && xv < t1) ? 1.0f : 0.0f;
  }
#pragma unroll
  for (int p = 1; p <= 3; ++p) {
    float inv = 1.0f / ((float)p * h);
#pragma unroll
    for (int j = 0; j < 8; ++j) {
      if (j < 9 - p) {  // compile-time fold under unroll
        float tj = (float)(j - 3) * h - 1.0f;
        float tjp1 = (float)(j + p + 1 - 3) * h - 1.0f;
        Bb[j] = (xv - tj) * inv * Bb[j] + (tjp1 - xv) * inv * Bb[j + 1];
      }
    }
  }
#pragma unroll
  for (int m = 0; m < 6; ++m) B[m] = Bb[m];
}

// ---------------- Kernel 1: x -> [silu | 6 basis] f16, x4 vectorized ----------------
__global__ __launch_bounds__(256) void build_A(const float* __restrict__ x,
                                               f16* __restrict__ Aa) {
  int idx = (blockIdx.x * 256 + threadIdx.x) * 4;  // 4 consecutive i, exact grid
  float4 xv = *(const float4*)(x + idx);
  int n = idx / DIN;
  int i = idx - n * DIN;  // multiple of 4; all 4 elems share n (DIN % 4 == 0)

  float B0[6], B1[6], B2[6], B3[6];
  float s0, s1, s2, s3;
  spline6(xv.x, B0, s0);
  spline6(xv.y, B1, s1);
  spline6(xv.z, B2, s2);
  spline6(xv.w, B3, s3);

  size_t base = (size_t)n * KAUG + i;  // 8B-aligned f16 stores
  f16x4 sv = {(f16)s0, (f16)s1, (f16)s2, (f16)s3};
  *(f16x4*)(Aa + base) = sv;
#pragma unroll
  for (int m = 0; m < 6; ++m) {
    f16x4 bv = {(f16)B0[m], (f16)B1[m], (f16)B2[m], (f16)B3[m]};
    *(f16x4*)(Aa + base + (size_t)(m + 1) * DIN) = bv;
  }
}

// ---------------- Kernel 2: pack weights ----------------
__global__ __launch_bounds__(256) void build_W(const float* __restrict__ sb,
                                               const float* __restrict__ ssp,
                                               const float* __restrict__ coef,
                                               f16* __restrict__ Wa) {
  int idx = blockIdx.x * 256 + threadIdx.x;  // o*768 + i, exact grid
  float b = sb[idx];
  float sp = ssp[idx];
  int o = idx / DIN;
  int i = idx - o * DIN;
  size_t base = (size_t)o * KAUG + i;
  Wa[base] = (f16)b;
#pragma unroll
  for (int m = 0; m < 6; ++m)
    Wa[base + (size_t)(m + 1) * DIN] = (f16)(sp * coef[(size_t)idx * 6 + m]);
}

// ---------------- Kernel 3: GEMM C = A_aug * W_aug^T + bias ----------------
// BM=64 x BN=128 tile, 4 waves (2x2; each wave 32x64 out), BK=32, dbuf 2-phase.
// Grid = 768 blocks = exactly 3 blocks/CU (12 waves/CU, uniform -> no tail
// imbalance; cross-block overlap hides the barrier vmcnt drain, m114 mechanism).
// Chunked XCD swizzle: 768 % 8 == 0 -> bijective; each XCD gets 96 consecutive
// work-ids = 16 A-panels x 6 cols, so the 6 column-blocks sharing an A-panel
// land on the SAME XCD's L2, and all 96 co-resident blocks share W's K-window.
__global__ __launch_bounds__(256) void kan_gemm(const f16* __restrict__ A,
                                                const f16* __restrict__ W,
                                                const float* __restrict__ bias,
                                                float* __restrict__ out) {
  __shared__ alignas(16) f16 As0[BM * BK];  // 4 KB
  __shared__ alignas(16) f16 As1[BM * BK];  // 4 KB
  __shared__ alignas(16) f16 Bs0[BN * BK];  // 8 KB
  __shared__ alignas(16) f16 Bs1[BN * BK];  // 8 KB  (24 KB total)

  const int tid = threadIdx.x;
  const int wave = tid >> 6;
  const int lane = tid & 63;

  // XCD-chunked swizzle (hardware: linear bid -> XCD bid%8)
  const int bid = blockIdx.x;
  const int wg = (bid & 7) * (NBLK / 8) + (bid >> 3);
  const int col = wg % 6;        // N-block
  const int panel = wg / 6;      // M-panel
  const int m0 = panel * BM;
  const int n0 = col * BN;

  const int wm = (wave >> 1) * 32;  // 2x2 wave grid, wave tile 32x64
  const int wn = (wave & 1) * 64;
  const int r = lane & 15;
  const int q = lane >> 4;

  f32x4 acc[2][4] = {};

  // staging: chunk c covers 16B at LDS byte c*16; row = c>>2, kblk = c&3
  const int c0 = wave * 64 + lane;           // 0..255
  const int rowS0 = c0 >> 2, kb0 = c0 & 3;   // rows 0..63
  const int c1 = c0 + 256;
  const int rowS1 = c1 >> 2, kb1 = c1 & 3;   // rows 64..127 (B only)

  const f16* gA0 = A + (size_t)(m0 + rowS0) * KAUG + kb0 * 8;
  const f16* gB0 = W + (size_t)(n0 + rowS0) * KAUG + kb0 * 8;
  const f16* gB1 = W + (size_t)(n0 + rowS1) * KAUG + kb1 * 8;

  const int wo = wave * 512;  // wave-uniform LDS base (f16 units; 1024 B)

#define STAGE(AS, BS, ktile)                                                             \
  do {                                                                                   \
    const int koff = (ktile)*BK;                                                         \
    __builtin_amdgcn_global_load_lds((gvoid*)(gA0 + koff), (lvoid*)(AS + wo), 16, 0, 0); \
    __builtin_amdgcn_global_load_lds((gvoid*)(gB0 + koff), (lvoid*)(BS + wo), 16, 0, 0); \
    __builtin_amdgcn_global_load_lds((gvoid*)(gB1 + koff), (lvoid*)(BS + wo + 2048), 16, \
                                     0, 0);                                              \
  } while (0)

#define COMPUTE(AS, BS)                                                                  \
  do {                                                                                   \
    f16x8 af[2], bf[4];                                                                  \
    _Pragma("unroll") for (int mi = 0; mi < 2; ++mi) af[mi] =                            \
        *(const f16x8*)&AS[(wm + mi * 16 + r) * BK + q * 8];                             \
    _Pragma("unroll") for (int ni = 0; ni < 4; ++ni) bf[ni] =                            \
        *(const f16x8*)&BS[(wn + ni * 16 + r) * BK + q * 8];                             \
    _Pragma("unroll") for (int mi = 0; mi < 2; ++mi) _Pragma("unroll") for (int ni = 0;  \
                                                                            ni < 4;     \
                                                                            ++ni)       \
        acc[mi][ni] =                                                                    \
        __builtin_amdgcn_mfma_f32_16x16x32_f16(af[mi], bf[ni], acc[mi][ni], 0, 0, 0);    \
  } while (0)

  STAGE(As0, Bs0, 0);
  __syncthreads();  // drain prologue staging

  for (int kt = 0; kt < KT; kt += 2) {  // KT even; kt+1 always valid
    STAGE(As1, Bs1, kt + 1);            // prefetch next tile (async, in flight)
    COMPUTE(As0, Bs0);
    __syncthreads();                    // drains As1/Bs1 staging + read-fence As0/Bs0
    if (kt + 2 < KT) STAGE(As0, Bs0, kt + 2);
    COMPUTE(As1, Bs1);
    __syncthreads();
  }

#undef STAGE
#undef COMPUTE

  // epilogue: D mapping col = lane&15, row = q*4 + reg
#pragma unroll
  for (int mi = 0; mi < 2; ++mi) {
#pragma unroll
    for (int ni = 0; ni < 4; ++ni) {
      const int gcol = n0 + wn + ni * 16 + r;
      const float bv = bias[gcol];
#pragma unroll
      for (int rg = 0; rg < 4; ++rg) {
        const int grow = m0 + wm + mi * 16 + q * 4 + rg;
        out[(size_t)grow * DOUT + gcol] = acc[mi][ni][rg] + bv;
      }
    }
  }
}

extern "C" void kernel_launch(void* const* d_in, const int* in_sizes, int n_in,
                              void* d_out, int out_size, void* d_ws, size_t ws_size,
                              hipStream_t stream) {
  const float* x = (const float*)d_in[0];           // (4,2048,768)
  const float* coef = (const float*)d_in[1];        // (768,768,6)
  const float* scale_base = (const float*)d_in[2];  // (768,768)
  const float* scale_sp = (const float*)d_in[3];    // (768,768)
  const float* bias = (const float*)d_in[4];        // (768,)
  float* out = (float*)d_out;                       // (8192,768)

  f16* Aa = (f16*)d_ws;                                     // 8192*5376*2 = 88.1 MB
  f16* Wa = (f16*)((char*)d_ws + (size_t)NTOK * KAUG * 2);  // 768*5376*2  = 8.3 MB

  build_A<<<(NTOK * DIN) / (256 * 4), 256, 0, stream>>>(x, Aa);
  build_W<<<(DOUT * DIN) / 256, 256, 0, stream>>>(scale_base, scale_sp, coef, Wa);
  kan_gemm<<<NBLK, 256, 0, stream>>>(Aa, Wa, bias, out);
}